// Round 6
// baseline (580.965 us; speedup 1.0000x reference)
//
#include <hip/hip_runtime.h>
#include <math.h>

#define L_SEQ 4096
#define D_HEAD 64
#define M_WIN 128
#define WIN 257              // 2*M+1
#define QB 8                 // query rows per block
#define W 264                // WIN + QB - 1
#define WF4 66               // W/4
#define SCALE 0.125f         // 1/sqrt(64)

// Barrier that drains LDS ops only — global stores stay in flight.
static __device__ __forceinline__ void barrier_lgkm() {
    asm volatile("s_waitcnt lgkmcnt(0)" ::: "memory");
    __builtin_amdgcn_s_barrier();
    asm volatile("" ::: "memory");
    __builtin_amdgcn_sched_barrier(0);
}

static __device__ __forceinline__ unsigned bfr(float x) {      // f32 -> bf16, RNE
    unsigned u = __float_as_uint(x);
    return (u + 0x7fffu + ((u >> 16) & 1u)) >> 16;
}
static __device__ __forceinline__ unsigned bfpack(float lo, float hi) {
    return bfr(lo) | (bfr(hi) << 16);
}

// 8 bf16 (one uint4 chunk) dotted against 8 f32 q values, for 2 q rows.
static __device__ __forceinline__ void dot2(uint4 Kc,
        float4 qa0, float4 qa1, float4 qb0, float4 qb1, float& sa, float& sb) {
    float e0 = __uint_as_float(Kc.x << 16);
    float e1 = __uint_as_float(Kc.x & 0xffff0000u);
    float e2 = __uint_as_float(Kc.y << 16);
    float e3 = __uint_as_float(Kc.y & 0xffff0000u);
    float e4 = __uint_as_float(Kc.z << 16);
    float e5 = __uint_as_float(Kc.z & 0xffff0000u);
    float e6 = __uint_as_float(Kc.w << 16);
    float e7 = __uint_as_float(Kc.w & 0xffff0000u);
    sa += qa0.x*e0 + qa0.y*e1 + qa0.z*e2 + qa0.w*e3
        + qa1.x*e4 + qa1.y*e5 + qa1.z*e6 + qa1.w*e7;
    sb += qb0.x*e0 + qb0.y*e1 + qb0.z*e2 + qb0.w*e3
        + qb1.x*e4 + qb1.y*e5 + qb1.z*e6 + qb1.w*e7;
}

__global__ __launch_bounds__(256, 3) void win_attn_kernel(
    const float* __restrict__ Q, const float* __restrict__ K,
    const float* __restrict__ V, float* __restrict__ OutO,
    float* __restrict__ OutA)
{
    extern __shared__ float smem[];
    // K tile: 264 rows x 8 uint4 chunks (8 bf16 each), chunk-swizzled.
    uint4*  k_su = (uint4*)smem;                       // 2112 uint4 = 33792 B
    float*  att  = smem + 2112 * 4;                    // [QB][W] f32 = 8448 B
    float*  q_s  = att + QB * W;                       // [QB][68] f32 = 2176 B
    float4* att4 = (float4*)att;
    float4* q_s4 = (float4*)q_s;

    const int t  = threadIdx.x;
    const int w  = t >> 6;
    const int ln = t & 63;

    // XCD-bijective swizzle: each XCD owns one batch (512 contiguous q-tiles).
    const int bid = (blockIdx.x & 7) * 512 + (blockIdx.x >> 3);
    const int b   = bid >> 9;
    const int q0  = (bid & 511) * QB;

    int s0 = q0 - M_WIN;
    if (s0 < 0) s0 = 0;
    if (s0 > L_SEQ - WIN) s0 = L_SEQ - WIN;
    const int wcount = (L_SEQ - s0 < W) ? (L_SEQ - s0) : W;

    const int zlo = s0 >> 2;                           // f4 window start
    const int zhi = ((s0 & 3) == 0) ? (zlo + WF4) : 1024;

    // ---------------- Phase A: stage Q (f32, padded) + K (bf16, swizzled) ---
    if (t < QB * 16) {
        const float4* Qg = (const float4*)(Q + ((size_t)(b * L_SEQ + q0)) * D_HEAD);
        q_s4[(t >> 4) * 17 + (t & 15)] = Qg[t];
    }
    {
        const float4* Kg = (const float4*)(K + ((size_t)(b * L_SEQ + s0)) * D_HEAD);
        #pragma unroll 3
        for (int idx = t; idx < 264 * 8; idx += 256) {
            int row = idx >> 3, c8 = idx & 7;
            int gr  = (row < wcount) ? row : wcount - 1;
            float4 a = Kg[(size_t)gr * 16 + c8 * 2];
            float4 bb = Kg[(size_t)gr * 16 + c8 * 2 + 1];
            uint4 d;
            d.x = bfpack(a.x, a.y);  d.y = bfpack(a.z, a.w);
            d.z = bfpack(bb.x, bb.y); d.w = bfpack(bb.z, bb.w);
            k_su[row * 8 + (c8 ^ (row & 7))] = d;
        }
    }
    barrier_lgkm();

    // ---------------- Phase B: scores, 2q x 4col register tile per lane -----
    {
        const int qg = ln >> 4;            // q rows {2qg, 2qg+1}
        const int cg = ln & 15;
        #pragma unroll 1
        for (int base = 64 * w; base < W; base += 256) {
            int col0 = base + 4 * cg;
            if (col0 < W) {
                const uint4* kc0 = k_su + (size_t)(col0 + 0) * 8;
                const uint4* kc1 = k_su + (size_t)(col0 + 1) * 8;
                const uint4* kc2 = k_su + (size_t)(col0 + 2) * 8;
                const uint4* kc3 = k_su + (size_t)(col0 + 3) * 8;
                const int m0 = (col0 + 0) & 7, m1 = (col0 + 1) & 7;
                const int m2 = (col0 + 2) & 7, m3 = (col0 + 3) & 7;
                float s00=0.f,s01=0.f,s02=0.f,s03=0.f;   // q row 2qg, cols 0..3
                float s10=0.f,s11=0.f,s12=0.f,s13=0.f;   // q row 2qg+1
                #pragma unroll
                for (int c8 = 0; c8 < 8; ++c8) {
                    float4 qa0 = q_s4[(2*qg)   * 17 + 2*c8];
                    float4 qa1 = q_s4[(2*qg)   * 17 + 2*c8 + 1];
                    float4 qb0 = q_s4[(2*qg+1) * 17 + 2*c8];
                    float4 qb1 = q_s4[(2*qg+1) * 17 + 2*c8 + 1];
                    dot2(kc0[c8 ^ m0], qa0,qa1,qb0,qb1, s00, s10);
                    dot2(kc1[c8 ^ m1], qa0,qa1,qb0,qb1, s01, s11);
                    dot2(kc2[c8 ^ m2], qa0,qa1,qb0,qb1, s02, s12);
                    dot2(kc3[c8 ^ m3], qa0,qa1,qb0,qb1, s03, s13);
                }
                float4 r0 = { s00*SCALE, s01*SCALE, s02*SCALE, s03*SCALE };
                float4 r1 = { s10*SCALE, s11*SCALE, s12*SCALE, s13*SCALE };
                att4[(2*qg)   * WF4 + (col0 >> 2)] = r0;
                att4[(2*qg+1) * WF4 + (col0 >> 2)] = r1;
            }
        }
    }
    barrier_lgkm();

    // ---------------- Phase C: masked softmax (wave w owns rows 2w, 2w+1) ---
    {
        const int q  = t >> 5;
        const int i  = t & 31;
        const int qg = q0 + q;
        int st = qg - M_WIN;
        if (st < 0) st = 0;
        if (st > L_SEQ - WIN) st = L_SEQ - WIN;
        const int lo = st - s0;

        float sv[9];
        float m = -1e30f;
        #pragma unroll
        for (int j = 0; j < 9; ++j) {
            int col = i + 32 * j;
            float s = -1e30f;
            if (col < W) {
                s = att[q * W + col];
                if (col < lo || col >= lo + WIN) s = -1e30f;
            }
            sv[j] = s;
            m = fmaxf(m, s);
        }
        #pragma unroll
        for (int k = 16; k >= 1; k >>= 1) m = fmaxf(m, __shfl_xor(m, k, 32));
        float sum = 0.f;
        #pragma unroll
        for (int j = 0; j < 9; ++j) {
            float e = (sv[j] <= -1e29f) ? 0.f : __expf(sv[j] - m);
            sv[j] = e;
            sum += e;
        }
        #pragma unroll
        for (int k = 16; k >= 1; k >>= 1) sum += __shfl_xor(sum, k, 32);
        const float inv = 1.f / sum;
        #pragma unroll
        for (int j = 0; j < 9; ++j) {
            int col = i + 32 * j;
            if (col < W) att[q * W + col] = sv[j] * inv;
        }
    }
    // No barrier: phase E's wave w reads exactly the rows it wrote in C.

    // ---------------- Phase E: PV; wave w -> q rows {2w, 2w+1} --------------
    {
        const int cq = ln >> 4;
        const int dg = ln & 15;
        const float4* Vg4 = (const float4*)(V + ((size_t)(b * L_SEQ + s0)) * D_HEAD);
        const float* arow0 = att + (2 * w) * W;
        const float* arow1 = arow0 + W;
        float4 acc0 = {0.f,0.f,0.f,0.f}, acc1 = {0.f,0.f,0.f,0.f};
        #pragma unroll 2
        for (int g = 0; g < WF4; ++g) {
            int col  = 4 * g + cq;
            int colc = (col < wcount) ? col : wcount - 1;   // att is 0 there
            float4 vv = Vg4[(size_t)colc * 16 + dg];
            float p0 = arow0[col];
            float p1 = arow1[col];
            acc0.x += p0 * vv.x; acc0.y += p0 * vv.y; acc0.z += p0 * vv.z; acc0.w += p0 * vv.w;
            acc1.x += p1 * vv.x; acc1.y += p1 * vv.y; acc1.z += p1 * vv.z; acc1.w += p1 * vv.w;
        }
        #pragma unroll
        for (int off = 16; off <= 32; off <<= 1) {
            acc0.x += __shfl_xor(acc0.x, off); acc0.y += __shfl_xor(acc0.y, off);
            acc0.z += __shfl_xor(acc0.z, off); acc0.w += __shfl_xor(acc0.w, off);
            acc1.x += __shfl_xor(acc1.x, off); acc1.y += __shfl_xor(acc1.y, off);
            acc1.z += __shfl_xor(acc1.z, off); acc1.w += __shfl_xor(acc1.w, off);
        }
        if (ln < 16) {
            float4* o4 = (float4*)(OutO + ((size_t)(b * L_SEQ + q0 + 2 * w)) * D_HEAD);
            o4[dg]      = acc0;
            o4[16 + dg] = acc1;
        }
    }

    // ---------------- Zeros: fire-and-forget, NO loads after this point -----
    {
        const float4 z = {0.f, 0.f, 0.f, 0.f};
        #pragma unroll 1
        for (int idx = t; idx < QB * 1024; idx += 256) {
            int ql  = idx >> 10;
            int f4i = idx & 1023;
            if (f4i < zlo || f4i >= zhi) {
                float4* rowp = (float4*)(OutA + ((size_t)(b * L_SEQ + q0 + ql)) * L_SEQ);
                rowp[f4i] = z;
            }
        }
    }
    barrier_lgkm();   // all att rows final (C) before cross-row window writes

    // ---------------- Phase D: window-only att writes -----------------------
    if ((s0 & 3) == 0) {
        #pragma unroll 1
        for (int idx = t; idx < QB * WF4; idx += 256) {
            int ql = idx / WF4;
            int c  = idx - ql * WF4;
            float4* rowp = (float4*)(OutA + ((size_t)(b * L_SEQ + q0 + ql)) * L_SEQ);
            rowp[zlo + c] = att4[ql * WF4 + c];
        }
    } else {   // s0 = 3839: window f4 span [959, 1024), scalar gather
        #pragma unroll 1
        for (int idx = t; idx < QB * 65; idx += 256) {
            int ql  = idx / 65;
            int c   = idx - ql * 65;
            int f4i = 959 + c;
            int u   = 4 * f4i - s0;
            const float* arow = att + ql * W;
            float4 wv;
            wv.x = (u     >= 0 && u     < W) ? arow[u]     : 0.f;
            wv.y = (u + 1 >= 0 && u + 1 < W) ? arow[u + 1] : 0.f;
            wv.z = (u + 2 >= 0 && u + 2 < W) ? arow[u + 2] : 0.f;
            wv.w = (u + 3 >= 0 && u + 3 < W) ? arow[u + 3] : 0.f;
            float4* rowp = (float4*)(OutA + ((size_t)(b * L_SEQ + q0 + ql)) * L_SEQ);
            rowp[f4i] = wv;
        }
    }
}

extern "C" void kernel_launch(void* const* d_in, const int* in_sizes, int n_in,
                              void* d_out, int out_size, void* d_ws, size_t ws_size,
                              hipStream_t stream) {
    const float* Q = (const float*)d_in[0];
    const float* K = (const float*)d_in[1];
    const float* V = (const float*)d_in[2];
    float* OutO = (float*)d_out;
    float* OutA = OutO + (size_t)8 * L_SEQ * D_HEAD;

    const int smem_bytes = 33792 + QB * W * 4 + QB * 68 * 4;   // 44416 B
    hipFuncSetAttribute((const void*)win_attn_kernel,
                        hipFuncAttributeMaxDynamicSharedMemorySize, smem_bytes);

    dim3 grid(8 * (L_SEQ / QB));
    dim3 block(256);
    win_attn_kernel<<<grid, block, smem_bytes, stream>>>(Q, K, V, OutO, OutA);
}

// Round 7
// 518.951 us; speedup vs baseline: 1.1195x; 1.1195x over previous
//
#include <hip/hip_runtime.h>
#include <math.h>

#define L_SEQ 4096
#define D_HEAD 64
#define M_WIN 128
#define WIN 257              // 2*M+1
#define QB 8                 // query rows per block
#define W 264                // WIN + QB - 1
#define WF4 66               // W/4
#define SCALE 0.125f         // 1/sqrt(64)

// Barrier draining LDS ops only (no later loads depend on in-flight stores
// across these barriers in this kernel, and no early global stores exist).
static __device__ __forceinline__ void barrier_lgkm() {
    asm volatile("s_waitcnt lgkmcnt(0)" ::: "memory");
    __builtin_amdgcn_s_barrier();
    asm volatile("" ::: "memory");
    __builtin_amdgcn_sched_barrier(0);
}

static __device__ __forceinline__ unsigned bfr(float x) {      // f32->bf16 RNE
    unsigned u = __float_as_uint(x);
    return (u + 0x7fffu + ((u >> 16) & 1u)) >> 16;
}
static __device__ __forceinline__ unsigned bfpack(float lo, float hi) {
    return bfr(lo) | (bfr(hi) << 16);
}

// one uint4 = 8 bf16 K elems, dotted vs 8 f32 q values for 2 q rows
static __device__ __forceinline__ void dot2(uint4 Kc,
        float4 qa0, float4 qa1, float4 qb0, float4 qb1, float& sa, float& sb) {
    float e0 = __uint_as_float(Kc.x << 16);
    float e1 = __uint_as_float(Kc.x & 0xffff0000u);
    float e2 = __uint_as_float(Kc.y << 16);
    float e3 = __uint_as_float(Kc.y & 0xffff0000u);
    float e4 = __uint_as_float(Kc.z << 16);
    float e5 = __uint_as_float(Kc.z & 0xffff0000u);
    float e6 = __uint_as_float(Kc.w << 16);
    float e7 = __uint_as_float(Kc.w & 0xffff0000u);
    sa += qa0.x*e0 + qa0.y*e1 + qa0.z*e2 + qa0.w*e3
        + qa1.x*e4 + qa1.y*e5 + qa1.z*e6 + qa1.w*e7;
    sb += qb0.x*e0 + qb0.y*e1 + qb0.z*e2 + qb0.w*e3
        + qb1.x*e4 + qb1.y*e5 + qb1.z*e6 + qb1.w*e7;
}

// K tile: [264 rows][8 uint4 slots], slot = c8 ^ ((row>>2)&7).
// Phase-B lanes read 4-col groups col0 = base+4*cg: (col0>>2)&7 varies over
// all 8 values across cg -> per instruction 16 lanes hit 8 slot-quads = all
// 32 banks, 2 lanes each (2-way = free). Staging writes: slot permuted
// within each row -> contiguous 1KB per wave, conflict-free.
__global__ __launch_bounds__(256, 3) void win_attn_kernel(
    const float* __restrict__ Q, const float* __restrict__ K,
    const float* __restrict__ V, float* __restrict__ OutO,
    float* __restrict__ OutA)
{
    extern __shared__ float smem[];
    uint4*  k_su = (uint4*)smem;                       // 2112 uint4 = 33792 B
    float*  att  = smem + 2112 * 4;                    // [QB][W]
    float*  q_s  = att + QB * W;                       // [QB][68] padded
    float4* att4 = (float4*)att;
    float4* q_s4 = (float4*)q_s;

    const int t  = threadIdx.x;
    const int w  = t >> 6;
    const int ln = t & 63;
    const int bid = blockIdx.x;        // native mapping (round-1 proved reuse)
    const int b   = bid >> 9;
    const int q0  = (bid & 511) * QB;

    int s0 = q0 - M_WIN;
    if (s0 < 0) s0 = 0;
    if (s0 > L_SEQ - WIN) s0 = L_SEQ - WIN;
    const int wcount = (L_SEQ - s0 < W) ? (L_SEQ - s0) : W;

    // ---------------- Phase A: stage Q (f32 padded) + K (bf16 swizzled) -----
    if (t < QB * 16) {
        const float4* Qg = (const float4*)(Q + ((size_t)(b * L_SEQ + q0)) * D_HEAD);
        q_s4[(t >> 4) * 17 + (t & 15)] = Qg[t];
    }
    {
        const float4* Kg = (const float4*)(K + ((size_t)(b * L_SEQ + s0)) * D_HEAD);
        #pragma unroll 3
        for (int idx = t; idx < 264 * 8; idx += 256) {
            int row = idx >> 3, c8 = idx & 7;
            int gr  = (row < wcount) ? row : wcount - 1;
            float4 a  = Kg[(size_t)gr * 16 + c8 * 2];
            float4 bb = Kg[(size_t)gr * 16 + c8 * 2 + 1];
            uint4 d;
            d.x = bfpack(a.x, a.y);   d.y = bfpack(a.z, a.w);
            d.z = bfpack(bb.x, bb.y); d.w = bfpack(bb.z, bb.w);
            k_su[row * 8 + (c8 ^ ((row >> 2) & 7))] = d;
        }
    }
    barrier_lgkm();

    // ---------------- Phase B: scores, 2q x 4col register tile per lane -----
    {
        const int qg = ln >> 4;            // q rows {2qg, 2qg+1}
        const int cg = ln & 15;
        #pragma unroll 1
        for (int base = 64 * w; base < W; base += 256) {
            int col0 = base + 4 * cg;
            if (col0 < W) {
                const int m = (col0 >> 2) & 7;     // same for cols col0..col0+3
                const uint4* kc0 = k_su + (size_t)(col0 + 0) * 8;
                const uint4* kc1 = k_su + (size_t)(col0 + 1) * 8;
                const uint4* kc2 = k_su + (size_t)(col0 + 2) * 8;
                const uint4* kc3 = k_su + (size_t)(col0 + 3) * 8;
                float s00=0.f,s01=0.f,s02=0.f,s03=0.f;
                float s10=0.f,s11=0.f,s12=0.f,s13=0.f;
                #pragma unroll
                for (int c8 = 0; c8 < 8; ++c8) {
                    int sc = c8 ^ m;
                    float4 qa0 = q_s4[(2*qg)   * 17 + 2*c8];
                    float4 qa1 = q_s4[(2*qg)   * 17 + 2*c8 + 1];
                    float4 qb0 = q_s4[(2*qg+1) * 17 + 2*c8];
                    float4 qb1 = q_s4[(2*qg+1) * 17 + 2*c8 + 1];
                    dot2(kc0[sc], qa0,qa1,qb0,qb1, s00, s10);
                    dot2(kc1[sc], qa0,qa1,qb0,qb1, s01, s11);
                    dot2(kc2[sc], qa0,qa1,qb0,qb1, s02, s12);
                    dot2(kc3[sc], qa0,qa1,qb0,qb1, s03, s13);
                }
                float4 r0 = { s00*SCALE, s01*SCALE, s02*SCALE, s03*SCALE };
                float4 r1 = { s10*SCALE, s11*SCALE, s12*SCALE, s13*SCALE };
                att4[(2*qg)   * WF4 + (col0 >> 2)] = r0;
                att4[(2*qg+1) * WF4 + (col0 >> 2)] = r1;
            }
        }
    }
    barrier_lgkm();

    // ---------------- Phase C: masked softmax (wave w -> rows 2w, 2w+1) -----
    {
        const int q  = t >> 5;
        const int i  = t & 31;
        const int qg = q0 + q;
        int st = qg - M_WIN;
        if (st < 0) st = 0;
        if (st > L_SEQ - WIN) st = L_SEQ - WIN;
        const int lo = st - s0;

        float sv[9];
        float m = -1e30f;
        #pragma unroll
        for (int j = 0; j < 9; ++j) {
            int col = i + 32 * j;
            float s = -1e30f;
            if (col < W) {
                s = att[q * W + col];
                if (col < lo || col >= lo + WIN) s = -1e30f;
            }
            sv[j] = s;
            m = fmaxf(m, s);
        }
        #pragma unroll
        for (int k = 16; k >= 1; k >>= 1) m = fmaxf(m, __shfl_xor(m, k, 32));
        float sum = 0.f;
        #pragma unroll
        for (int j = 0; j < 9; ++j) {
            float e = (sv[j] <= -1e29f) ? 0.f : __expf(sv[j] - m);
            sv[j] = e;
            sum += e;
        }
        #pragma unroll
        for (int k = 16; k >= 1; k >>= 1) sum += __shfl_xor(sum, k, 32);
        const float inv = 1.f / sum;
        #pragma unroll
        for (int j = 0; j < 9; ++j) {
            int col = i + 32 * j;
            if (col < W) att[q * W + col] = sv[j] * inv;
        }
    }
    // No barrier: phase E's wave w reads exactly the rows it wrote in C.

    // ---------------- Phase E: PV; wave w -> q rows {2w, 2w+1} --------------
    {
        const int cq = ln >> 4;
        const int dg = ln & 15;
        const float4* Vg4 = (const float4*)(V + ((size_t)(b * L_SEQ + s0)) * D_HEAD);
        const float* arow0 = att + (2 * w) * W;
        const float* arow1 = arow0 + W;
        float4 acc0 = {0.f,0.f,0.f,0.f}, acc1 = {0.f,0.f,0.f,0.f};
        #pragma unroll 2
        for (int g = 0; g < WF4; ++g) {
            int col  = 4 * g + cq;
            int colc = (col < wcount) ? col : wcount - 1;   // att is 0 there
            float4 vv = Vg4[(size_t)colc * 16 + dg];
            float p0 = arow0[col];
            float p1 = arow1[col];
            acc0.x += p0 * vv.x; acc0.y += p0 * vv.y; acc0.z += p0 * vv.z; acc0.w += p0 * vv.w;
            acc1.x += p1 * vv.x; acc1.y += p1 * vv.y; acc1.z += p1 * vv.z; acc1.w += p1 * vv.w;
        }
        #pragma unroll
        for (int off = 16; off <= 32; off <<= 1) {
            acc0.x += __shfl_xor(acc0.x, off); acc0.y += __shfl_xor(acc0.y, off);
            acc0.z += __shfl_xor(acc0.z, off); acc0.w += __shfl_xor(acc0.w, off);
            acc1.x += __shfl_xor(acc1.x, off); acc1.y += __shfl_xor(acc1.y, off);
            acc1.z += __shfl_xor(acc1.z, off); acc1.w += __shfl_xor(acc1.w, off);
        }
        if (ln < 16) {
            float4* o4 = (float4*)(OutO + ((size_t)(b * L_SEQ + q0 + 2 * w)) * D_HEAD);
            o4[dg]      = acc0;
            o4[16 + dg] = acc1;
        }
    }
    barrier_lgkm();   // all att rows final before cross-row streaming

    // ---------------- Phase D: dense full-row att stream (537 MB) -----------
    if ((s0 & 3) == 0) {
        #pragma unroll 1
        for (int ql = 0; ql < QB; ++ql) {
            float4* rowp = (float4*)(OutA + ((size_t)(b * L_SEQ + q0 + ql)) * L_SEQ);
            const float4* arow = (const float4*)(att + ql * W);
            const int zlo = s0 >> 2;
            #pragma unroll
            for (int jj = 0; jj < 4; ++jj) {
                int f4i = jj * 256 + t;
                int u4  = f4i - zlo;
                float4 wv = {0.f,0.f,0.f,0.f};
                if (u4 >= 0 && u4 < WF4) wv = arow[u4];     // aligned b128 read
                rowp[f4i] = wv;
            }
        }
    } else {   // rare top-edge blocks (s0 = 3839)
        #pragma unroll 1
        for (int ql = 0; ql < QB; ++ql) {
            float4* rowp = (float4*)(OutA + ((size_t)(b * L_SEQ + q0 + ql)) * L_SEQ);
            const float* arow = att + ql * W;
            #pragma unroll
            for (int jj = 0; jj < 4; ++jj) {
                int f4i = jj * 256 + t;
                int u   = 4 * f4i - s0;
                float4 wv;
                wv.x = (u     >= 0 && u     < W) ? arow[u]     : 0.f;
                wv.y = (u + 1 >= 0 && u + 1 < W) ? arow[u + 1] : 0.f;
                wv.z = (u + 2 >= 0 && u + 2 < W) ? arow[u + 2] : 0.f;
                wv.w = (u + 3 >= 0 && u + 3 < W) ? arow[u + 3] : 0.f;
                rowp[f4i] = wv;
            }
        }
    }
}

extern "C" void kernel_launch(void* const* d_in, const int* in_sizes, int n_in,
                              void* d_out, int out_size, void* d_ws, size_t ws_size,
                              hipStream_t stream) {
    const float* Q = (const float*)d_in[0];
    const float* K = (const float*)d_in[1];
    const float* V = (const float*)d_in[2];
    float* OutO = (float*)d_out;
    float* OutA = OutO + (size_t)8 * L_SEQ * D_HEAD;

    const int smem_bytes = 33792 + QB * W * 4 + QB * 68 * 4;   // 44416 B
    hipFuncSetAttribute((const void*)win_attn_kernel,
                        hipFuncAttributeMaxDynamicSharedMemorySize, smem_bytes);

    dim3 grid(8 * (L_SEQ / QB));
    dim3 block(256);
    win_attn_kernel<<<grid, block, smem_bytes, stream>>>(Q, K, V, OutO, OutA);
}

// Round 8
// 227.565 us; speedup vs baseline: 2.5530x; 2.2804x over previous
//
#include <hip/hip_runtime.h>
#include <math.h>

#define L_SEQ 4096
#define D_HEAD 64
#define M_WIN 128
#define WIN 257              // 2*M+1
#define QB 8                 // query rows per block
#define W 264                // WIN + QB - 1
#define WF4 66               // W/4
#define SCALE 0.125f         // 1/sqrt(64)

// K tile: [264 rows][16 float4 slots], slot = c4 ^ (row&15).
// Staging (16 lanes per row): slots permuted within the row -> contiguous
// 256B per 16 lanes, conflict-free. Phase-B reads (lane owns col, fixed c):
// slot = c ^ (col&15) covers all 16 values per 16 consecutive cols -> all
// bank-quads hit, 2-way only (free).
__global__ __launch_bounds__(256, 2) void win_attn_kernel(
    const float* __restrict__ Q, const float* __restrict__ K,
    const float* __restrict__ V, float* __restrict__ OutO,
    float* __restrict__ OutA)
{
    extern __shared__ float smem[];
    float4* k_s4 = (float4*)smem;            // [264][16] f4 = 67584 B
    float*  att  = smem + 264 * 64;          // [QB][W] = 8448 B
    float4* att4 = (float4*)att;

    const int t  = threadIdx.x;
    const int w  = t >> 6;                   // wave 0..3 -> q rows {2w, 2w+1}
    const int ln = t & 63;

    // XCD-bijective swizzle: each XCD owns one batch (sequential K/V walk).
    const int bid = (blockIdx.x & 7) * 512 + (blockIdx.x >> 3);
    const int b   = bid >> 9;
    const int q0  = (bid & 511) * QB;

    int s0 = q0 - M_WIN;
    if (s0 < 0) s0 = 0;
    if (s0 > L_SEQ - WIN) s0 = L_SEQ - WIN;
    const int wcount = (L_SEQ - s0 < W) ? (L_SEQ - s0) : W;

    // ---------------- Phase A: stage K (f32, swizzled); q rows -> registers -
    {
        const float4* Kg = (const float4*)(K + ((size_t)(b * L_SEQ + s0)) * D_HEAD);
        #pragma unroll 2
        for (int idx = t; idx < 264 * 16; idx += 256) {
            int row = idx >> 4, c4 = idx & 15;
            int gr  = (row < wcount) ? row : wcount - 1;
            k_s4[row * 16 + (c4 ^ (row & 15))] = Kg[(size_t)gr * 16 + c4];
        }
    }
    const int r0g = q0 + 2 * w;              // this wave's two global q rows
    const float qv0 = Q[((size_t)(b * L_SEQ) + r0g)     * D_HEAD + ln];
    const float qv1 = Q[((size_t)(b * L_SEQ) + r0g + 1) * D_HEAD + ln];
    __syncthreads();                         // the ONLY block-wide barrier

    // ---------------- Phase B: scores; lane owns cols cg*64+ln --------------
    float p0[5], p1[5];                      // scores for 5 col-groups x 2 rows
    {
        const float4* kp[5];
        int msk[5];
        #pragma unroll
        for (int cg = 0; cg < 5; ++cg) {
            int colr = cg * 64 + ln;
            int col  = (colr < W) ? colr : W - 1;   // clamped for memory
            kp[cg]  = k_s4 + (size_t)col * 16;
            msk[cg] = col & 15;
            p0[cg] = 0.f; p1[cg] = 0.f;
        }
        #pragma unroll
        for (int c = 0; c < 16; ++c) {
            // wave-uniform q broadcasts (readlane; q row is shared by the wave)
            float a0 = __shfl(qv0, 4*c+0), a1 = __shfl(qv0, 4*c+1),
                  a2 = __shfl(qv0, 4*c+2), a3 = __shfl(qv0, 4*c+3);
            float b0 = __shfl(qv1, 4*c+0), b1 = __shfl(qv1, 4*c+1),
                  b2 = __shfl(qv1, 4*c+2), b3 = __shfl(qv1, 4*c+3);
            #pragma unroll
            for (int cg = 0; cg < 5; ++cg) {
                float4 kk = kp[cg][c ^ msk[cg]];
                p0[cg] += a0*kk.x + a1*kk.y + a2*kk.z + a3*kk.w;
                p1[cg] += b0*kk.x + b1*kk.y + b2*kk.z + b3*kk.w;
            }
        }
        #pragma unroll
        for (int cg = 0; cg < 5; ++cg) { p0[cg] *= SCALE; p1[cg] *= SCALE; }
    }

    // ---------------- Phase C: in-register masked softmax (per wave) --------
    {
        int st0 = r0g - M_WIN;
        if (st0 < 0) st0 = 0;
        if (st0 > L_SEQ - WIN) st0 = L_SEQ - WIN;
        const int lo0 = st0 - s0;
        int st1 = r0g + 1 - M_WIN;
        if (st1 < 0) st1 = 0;
        if (st1 > L_SEQ - WIN) st1 = L_SEQ - WIN;
        const int lo1 = st1 - s0;

        float m0 = -1e30f, m1 = -1e30f;
        #pragma unroll
        for (int cg = 0; cg < 5; ++cg) {
            int colr = cg * 64 + ln;
            bool in0 = (colr >= lo0) && (colr < lo0 + WIN);
            bool in1 = (colr >= lo1) && (colr < lo1 + WIN);
            p0[cg] = in0 ? p0[cg] : -1e30f;
            p1[cg] = in1 ? p1[cg] : -1e30f;
            m0 = fmaxf(m0, p0[cg]);
            m1 = fmaxf(m1, p1[cg]);
        }
        #pragma unroll
        for (int off = 32; off >= 1; off >>= 1) {
            m0 = fmaxf(m0, __shfl_xor(m0, off));
            m1 = fmaxf(m1, __shfl_xor(m1, off));
        }
        float sum0 = 0.f, sum1 = 0.f;
        #pragma unroll
        for (int cg = 0; cg < 5; ++cg) {
            float e0 = (p0[cg] <= -1e29f) ? 0.f : __expf(p0[cg] - m0);
            float e1 = (p1[cg] <= -1e29f) ? 0.f : __expf(p1[cg] - m1);
            p0[cg] = e0; p1[cg] = e1;
            sum0 += e0; sum1 += e1;
        }
        #pragma unroll
        for (int off = 32; off >= 1; off >>= 1) {
            sum0 += __shfl_xor(sum0, off);
            sum1 += __shfl_xor(sum1, off);
        }
        const float inv0 = 1.f / sum0, inv1 = 1.f / sum1;
        #pragma unroll
        for (int cg = 0; cg < 5; ++cg) {
            int colr = cg * 64 + ln;
            if (colr < W) {
                att[(2 * w)     * W + colr] = p0[cg] * inv0;  // 0 outside window
                att[(2 * w + 1) * W + colr] = p1[cg] * inv1;
            }
        }
    }
    // No barrier: everything below reads only this wave's own att rows.

    // ---------------- Phase E: PV for rows {2w, 2w+1}; V from global --------
    {
        const int cq = ln >> 4;              // col offset within 4-group
        const int dg = ln & 15;              // d float4-group
        const float4* Vg4 = (const float4*)(V + ((size_t)(b * L_SEQ + s0)) * D_HEAD);
        const float* arow0 = att + (2 * w) * W;
        const float* arow1 = arow0 + W;
        float4 acc0 = {0.f,0.f,0.f,0.f}, acc1 = {0.f,0.f,0.f,0.f};
        #pragma unroll 2
        for (int g = 0; g < WF4; ++g) {
            int col  = 4 * g + cq;
            int colc = (col < wcount) ? col : wcount - 1;   // att is 0 there
            float4 vv = Vg4[(size_t)colc * 16 + dg];        // 1 KB coalesced/wave
            float v0 = arow0[col];
            float v1 = arow1[col];
            acc0.x += v0 * vv.x; acc0.y += v0 * vv.y; acc0.z += v0 * vv.z; acc0.w += v0 * vv.w;
            acc1.x += v1 * vv.x; acc1.y += v1 * vv.y; acc1.z += v1 * vv.z; acc1.w += v1 * vv.w;
        }
        #pragma unroll
        for (int off = 16; off <= 32; off <<= 1) {
            acc0.x += __shfl_xor(acc0.x, off); acc0.y += __shfl_xor(acc0.y, off);
            acc0.z += __shfl_xor(acc0.z, off); acc0.w += __shfl_xor(acc0.w, off);
            acc1.x += __shfl_xor(acc1.x, off); acc1.y += __shfl_xor(acc1.y, off);
            acc1.z += __shfl_xor(acc1.z, off); acc1.w += __shfl_xor(acc1.w, off);
        }
        if (ln < 16) {
            float4* o4 = (float4*)(OutO + ((size_t)(b * L_SEQ + r0g)) * D_HEAD);
            o4[dg]      = acc0;
            o4[16 + dg] = acc1;
        }
    }

    // ---------------- Phase D: dense stream of this wave's 2 att rows -------
    if ((s0 & 3) == 0) {
        const int zlo = s0 >> 2;
        #pragma unroll
        for (int r = 0; r < 2; ++r) {
            float4* rowp = (float4*)(OutA + ((size_t)(b * L_SEQ + r0g + r)) * L_SEQ);
            const float4* arow = att4 + (2 * w + r) * WF4;
            #pragma unroll 4
            for (int j = 0; j < 16; ++j) {
                int f4i = j * 64 + ln;
                int u4  = f4i - zlo;
                float4 wv = {0.f,0.f,0.f,0.f};
                if (u4 >= 0 && u4 < WF4) wv = arow[u4];     // aligned b128 read
                rowp[f4i] = wv;                             // 1 KB/instr, clean
            }
        }
    } else {   // rare top-edge blocks (s0 = 3839)
        #pragma unroll
        for (int r = 0; r < 2; ++r) {
            float4* rowp = (float4*)(OutA + ((size_t)(b * L_SEQ + r0g + r)) * L_SEQ);
            const float* arow = att + (2 * w + r) * W;
            #pragma unroll 2
            for (int j = 0; j < 16; ++j) {
                int f4i = j * 64 + ln;
                int u   = 4 * f4i - s0;
                float4 wv;
                wv.x = (u     >= 0 && u     < W) ? arow[u]     : 0.f;
                wv.y = (u + 1 >= 0 && u + 1 < W) ? arow[u + 1] : 0.f;
                wv.z = (u + 2 >= 0 && u + 2 < W) ? arow[u + 2] : 0.f;
                wv.w = (u + 3 >= 0 && u + 3 < W) ? arow[u + 3] : 0.f;
                rowp[f4i] = wv;
            }
        }
    }
}

extern "C" void kernel_launch(void* const* d_in, const int* in_sizes, int n_in,
                              void* d_out, int out_size, void* d_ws, size_t ws_size,
                              hipStream_t stream) {
    const float* Q = (const float*)d_in[0];
    const float* K = (const float*)d_in[1];
    const float* V = (const float*)d_in[2];
    float* OutO = (float*)d_out;
    float* OutA = OutO + (size_t)8 * L_SEQ * D_HEAD;

    const int smem_bytes = 264 * 64 * 4 + QB * W * 4;   // 76032 B
    hipFuncSetAttribute((const void*)win_attn_kernel,
                        hipFuncAttributeMaxDynamicSharedMemorySize, smem_bytes);

    dim3 grid(8 * (L_SEQ / QB));
    dim3 block(256);
    win_attn_kernel<<<grid, block, smem_bytes, stream>>>(Q, K, V, OutO, OutA);
}

// Round 9
// 217.858 us; speedup vs baseline: 2.6667x; 1.0446x over previous
//
#include <hip/hip_runtime.h>
#include <math.h>

#define L_SEQ 4096
#define D_HEAD 64
#define M_WIN 128
#define WIN 257              // 2*M+1
#define QB 8                 // query rows per block
#define W 264                // WIN + QB - 1
#define WF4 66               // W/4
#define ATTS 272             // padded att row stride (floats); f4 stride 68
#define SCALE 0.125f         // 1/sqrt(64)

// wave-uniform lane read via VALU (v_readlane -> SGPR), not LDS pipe
#define RL(v, i) __uint_as_float(__builtin_amdgcn_readlane(__float_as_uint(v), (i)))

// K tile: [264 rows][16 float4 slots], slot = c4 ^ (row&15).
// Staging: slots permuted within each row -> conflict-free. Phase-B reads
// (lane owns col, fixed c): slot = c ^ (col&15) varies over all 16 values
// across 16 consecutive cols -> all bank-quads covered, 2-way only (free).
__global__ __launch_bounds__(256, 2) void win_attn_kernel(
    const float* __restrict__ Q, const float* __restrict__ K,
    const float* __restrict__ V, float* __restrict__ OutO,
    float* __restrict__ OutA)
{
    extern __shared__ float smem[];
    float4* k_s4 = (float4*)smem;            // [264][16] f4 = 67584 B
    float*  att  = smem + 264 * 64;          // [QB][ATTS] = 8704 B

    const int t  = threadIdx.x;
    const int w  = t >> 6;                   // wave 0..3 -> q rows {2w, 2w+1}
    const int ln = t & 63;

    // XCD-bijective swizzle: each XCD owns one batch (sequential K/V walk).
    const int bid = (blockIdx.x & 7) * 512 + (blockIdx.x >> 3);
    const int b   = bid >> 9;
    const int q0  = (bid & 511) * QB;

    int s0 = q0 - M_WIN;
    if (s0 < 0) s0 = 0;
    if (s0 > L_SEQ - WIN) s0 = L_SEQ - WIN;
    const int wcount = (L_SEQ - s0 < W) ? (L_SEQ - s0) : W;

    // ---------------- Phase A: stage K (f32, swizzled); q rows -> registers -
    {
        const float4* Kg = (const float4*)(K + ((size_t)(b * L_SEQ + s0)) * D_HEAD);
        #pragma unroll 2
        for (int idx = t; idx < 264 * 16; idx += 256) {
            int row = idx >> 4, c4 = idx & 15;
            int gr  = (row < wcount) ? row : wcount - 1;
            k_s4[row * 16 + (c4 ^ (row & 15))] = Kg[(size_t)gr * 16 + c4];
        }
    }
    const int r0g = q0 + 2 * w;              // this wave's two global q rows
    const float qv0 = Q[((size_t)(b * L_SEQ) + r0g)     * D_HEAD + ln];
    const float qv1 = Q[((size_t)(b * L_SEQ) + r0g + 1) * D_HEAD + ln];
    // zero the att row pad (cols 264..271) for vectorized phase E reads
    if (ln < 16) {
        int r = 2 * w + (ln >> 3);
        att[r * ATTS + 264 + (ln & 7)] = 0.f;
    }
    __syncthreads();                         // the ONLY block-wide barrier

    // ---------------- Phase B: scores; lane owns cols cg*64+ln --------------
    float p0[5], p1[5];
    {
        const float4* kp[5];
        int msk[5];
        #pragma unroll
        for (int cg = 0; cg < 5; ++cg) {
            int colr = cg * 64 + ln;
            int col  = (colr < W) ? colr : W - 1;   // clamped for memory
            kp[cg]  = k_s4 + (size_t)col * 16;
            msk[cg] = col & 15;
            p0[cg] = 0.f; p1[cg] = 0.f;
        }
        #pragma unroll
        for (int c = 0; c < 16; ++c) {
            // wave-uniform q broadcasts via v_readlane (VALU/SGPR, no LDS pipe)
            float a0 = RL(qv0, 4*c+0), a1 = RL(qv0, 4*c+1),
                  a2 = RL(qv0, 4*c+2), a3 = RL(qv0, 4*c+3);
            float b0 = RL(qv1, 4*c+0), b1 = RL(qv1, 4*c+1),
                  b2 = RL(qv1, 4*c+2), b3 = RL(qv1, 4*c+3);
            #pragma unroll
            for (int cg = 0; cg < 5; ++cg) {
                float4 kk = kp[cg][c ^ msk[cg]];
                p0[cg] += a0*kk.x + a1*kk.y + a2*kk.z + a3*kk.w;
                p1[cg] += b0*kk.x + b1*kk.y + b2*kk.z + b3*kk.w;
            }
        }
        #pragma unroll
        for (int cg = 0; cg < 5; ++cg) { p0[cg] *= SCALE; p1[cg] *= SCALE; }
    }

    // ---------------- Phase C: in-register masked softmax (per wave) --------
    {
        int st0 = r0g - M_WIN;
        if (st0 < 0) st0 = 0;
        if (st0 > L_SEQ - WIN) st0 = L_SEQ - WIN;
        const int lo0 = st0 - s0;
        int st1 = r0g + 1 - M_WIN;
        if (st1 < 0) st1 = 0;
        if (st1 > L_SEQ - WIN) st1 = L_SEQ - WIN;
        const int lo1 = st1 - s0;

        float m0 = -1e30f, m1 = -1e30f;
        #pragma unroll
        for (int cg = 0; cg < 5; ++cg) {
            int colr = cg * 64 + ln;
            bool in0 = (colr >= lo0) && (colr < lo0 + WIN);
            bool in1 = (colr >= lo1) && (colr < lo1 + WIN);
            p0[cg] = in0 ? p0[cg] : -1e30f;
            p1[cg] = in1 ? p1[cg] : -1e30f;
            m0 = fmaxf(m0, p0[cg]);
            m1 = fmaxf(m1, p1[cg]);
        }
        #pragma unroll
        for (int off = 32; off >= 1; off >>= 1) {
            m0 = fmaxf(m0, __shfl_xor(m0, off));
            m1 = fmaxf(m1, __shfl_xor(m1, off));
        }
        float sum0 = 0.f, sum1 = 0.f;
        #pragma unroll
        for (int cg = 0; cg < 5; ++cg) {
            float e0 = (p0[cg] <= -1e29f) ? 0.f : __expf(p0[cg] - m0);
            float e1 = (p1[cg] <= -1e29f) ? 0.f : __expf(p1[cg] - m1);
            p0[cg] = e0; p1[cg] = e1;
            sum0 += e0; sum1 += e1;
        }
        #pragma unroll
        for (int off = 32; off >= 1; off >>= 1) {
            sum0 += __shfl_xor(sum0, off);
            sum1 += __shfl_xor(sum1, off);
        }
        const float inv0 = 1.f / sum0, inv1 = 1.f / sum1;
        #pragma unroll
        for (int cg = 0; cg < 5; ++cg) {
            int colr = cg * 64 + ln;
            if (colr < W) {
                att[(2 * w)     * ATTS + colr] = p0[cg] * inv0;  // 0 outside win
                att[(2 * w + 1) * ATTS + colr] = p1[cg] * inv1;
            }
        }
    }
    // No barrier: everything below reads only this wave's own att rows.

    // ---------------- Phase E: PV; vectorized att reads (b128 per 4 cols) ---
    {
        const int cq = ln >> 4;              // which f4 of the 16-col group
        const int dg = ln & 15;              // d float4-group
        const float4* Vg4 = (const float4*)(V + ((size_t)(b * L_SEQ + s0)) * D_HEAD);
        const float4* a4r0 = (const float4*)(att + (2 * w) * ATTS);
        const float4* a4r1 = (const float4*)(att + (2 * w + 1) * ATTS);
        float4 acc0 = {0.f,0.f,0.f,0.f}, acc1 = {0.f,0.f,0.f,0.f};
        #pragma unroll 2
        for (int G = 0; G < 17; ++G) {       // 17*16 = 272 cols (pad p = 0)
            float4 pa = a4r0[4 * G + cq];    // 4 p-values for this lane's cols
            float4 pb = a4r1[4 * G + cq];
            #pragma unroll
            for (int e = 0; e < 4; ++e) {
                int col  = 16 * G + 4 * cq + e;
                int colc = (col < wcount) ? col : wcount - 1;   // p is 0 there
                float4 vv = Vg4[(size_t)colc * 16 + dg];
                float fa = (e == 0) ? pa.x : (e == 1) ? pa.y : (e == 2) ? pa.z : pa.w;
                float fb = (e == 0) ? pb.x : (e == 1) ? pb.y : (e == 2) ? pb.z : pb.w;
                acc0.x += fa * vv.x; acc0.y += fa * vv.y;
                acc0.z += fa * vv.z; acc0.w += fa * vv.w;
                acc1.x += fb * vv.x; acc1.y += fb * vv.y;
                acc1.z += fb * vv.z; acc1.w += fb * vv.w;
            }
        }
        #pragma unroll
        for (int off = 16; off <= 32; off <<= 1) {
            acc0.x += __shfl_xor(acc0.x, off); acc0.y += __shfl_xor(acc0.y, off);
            acc0.z += __shfl_xor(acc0.z, off); acc0.w += __shfl_xor(acc0.w, off);
            acc1.x += __shfl_xor(acc1.x, off); acc1.y += __shfl_xor(acc1.y, off);
            acc1.z += __shfl_xor(acc1.z, off); acc1.w += __shfl_xor(acc1.w, off);
        }
        if (ln < 16) {
            float4* o4 = (float4*)(OutO + ((size_t)(b * L_SEQ + r0g)) * D_HEAD);
            o4[dg]      = acc0;
            o4[16 + dg] = acc1;
        }
    }

    // ---------------- Phase D: dense stream of this wave's 2 att rows -------
    if ((s0 & 3) == 0) {
        const int zlo = s0 >> 2;
        #pragma unroll
        for (int r = 0; r < 2; ++r) {
            float4* rowp = (float4*)(OutA + ((size_t)(b * L_SEQ + r0g + r)) * L_SEQ);
            const float4* arow = (const float4*)(att + (2 * w + r) * ATTS);
            #pragma unroll 4
            for (int j = 0; j < 16; ++j) {
                int f4i = j * 64 + ln;
                int u4  = f4i - zlo;
                float4 wv = {0.f,0.f,0.f,0.f};
                if (u4 >= 0 && u4 < WF4) wv = arow[u4];     // aligned b128 read
                rowp[f4i] = wv;                             // 1 KB/instr, clean
            }
        }
    } else {   // rare top-edge blocks (s0 = 3839)
        #pragma unroll
        for (int r = 0; r < 2; ++r) {
            float4* rowp = (float4*)(OutA + ((size_t)(b * L_SEQ + r0g + r)) * L_SEQ);
            const float* arow = att + (2 * w + r) * ATTS;
            #pragma unroll 2
            for (int j = 0; j < 16; ++j) {
                int f4i = j * 64 + ln;
                int u   = 4 * f4i - s0;
                float4 wv;
                wv.x = (u     >= 0 && u     < W) ? arow[u]     : 0.f;
                wv.y = (u + 1 >= 0 && u + 1 < W) ? arow[u + 1] : 0.f;
                wv.z = (u + 2 >= 0 && u + 2 < W) ? arow[u + 2] : 0.f;
                wv.w = (u + 3 >= 0 && u + 3 < W) ? arow[u + 3] : 0.f;
                rowp[f4i] = wv;
            }
        }
    }
}

extern "C" void kernel_launch(void* const* d_in, const int* in_sizes, int n_in,
                              void* d_out, int out_size, void* d_ws, size_t ws_size,
                              hipStream_t stream) {
    const float* Q = (const float*)d_in[0];
    const float* K = (const float*)d_in[1];
    const float* V = (const float*)d_in[2];
    float* OutO = (float*)d_out;
    float* OutA = OutO + (size_t)8 * L_SEQ * D_HEAD;

    const int smem_bytes = 264 * 64 * 4 + QB * ATTS * 4;   // 76288 B
    hipFuncSetAttribute((const void*)win_attn_kernel,
                        hipFuncAttributeMaxDynamicSharedMemorySize, smem_bytes);

    dim3 grid(8 * (L_SEQ / QB));
    dim3 block(256);
    win_attn_kernel<<<grid, block, smem_bytes, stream>>>(Q, K, V, OutO, OutA);
}

// Round 10
// 169.290 us; speedup vs baseline: 3.4318x; 1.2869x over previous
//
#include <hip/hip_runtime.h>
#include <math.h>

#define L_SEQ 4096
#define D_HEAD 64
#define M_WIN 128
#define WIN 257              // 2*M+1
#define QB 8                 // query rows per block
#define W 264                // WIN + QB - 1
#define WF4 66               // W/4
#define ATTS 272             // padded att row stride (floats); f4 stride 68
#define SCALE 0.125f         // 1/sqrt(64)

// wave-uniform lane read via VALU (v_readlane -> SGPR), not LDS pipe
#define RL(v, i) __uint_as_float(__builtin_amdgcn_readlane(__float_as_uint(v), (i)))

static __device__ __forceinline__ unsigned bfr(float x) {      // f32->bf16 RNE
    unsigned u = __float_as_uint(x);
    return (u + 0x7fffu + ((u >> 16) & 1u)) >> 16;
}
static __device__ __forceinline__ unsigned bfpack(float lo, float hi) {
    return bfr(lo) | (bfr(hi) << 16);
}

// K tile: [264 rows][8 uint4 slots], slot = c8 ^ (row&7); one uint4 = 8 bf16.
// Phase-B reads (lane owns col, fixed c8): slot varies over all 8 values per
// 8 consecutive cols -> uniform bank load (8 lanes/bank = b128 minimum, no
// conflict). Staging writes: 8 threads per row hit 8 distinct slots.
__global__ __launch_bounds__(256, 3) void win_attn_kernel(
    const float* __restrict__ Q, const float* __restrict__ K,
    const float* __restrict__ V, float* __restrict__ OutO,
    float* __restrict__ OutA)
{
    extern __shared__ float smem[];
    uint4* k_su = (uint4*)smem;              // [264][8] uint4 = 33792 B
    float* att  = smem + 2112 * 4;           // [QB][ATTS] = 8704 B

    const int t  = threadIdx.x;
    const int w  = t >> 6;                   // wave 0..3 -> q rows {2w, 2w+1}
    const int ln = t & 63;

    // XCD-bijective swizzle: each XCD owns one batch (sequential K/V walk).
    const int bid = (blockIdx.x & 7) * 512 + (blockIdx.x >> 3);
    const int b   = bid >> 9;
    const int q0  = (bid & 511) * QB;

    int s0 = q0 - M_WIN;
    if (s0 < 0) s0 = 0;
    if (s0 > L_SEQ - WIN) s0 = L_SEQ - WIN;
    const int wcount = (L_SEQ - s0 < W) ? (L_SEQ - s0) : W;

    // ---------------- Phase A: stage K (bf16, swizzled); q rows -> registers
    {
        const float4* Kg = (const float4*)(K + ((size_t)(b * L_SEQ + s0)) * D_HEAD);
        #pragma unroll 3
        for (int idx = t; idx < 264 * 8; idx += 256) {
            int row = idx >> 3, c8 = idx & 7;
            int gr  = (row < wcount) ? row : wcount - 1;
            float4 a  = Kg[(size_t)gr * 16 + c8 * 2];
            float4 bb = Kg[(size_t)gr * 16 + c8 * 2 + 1];
            uint4 d;
            d.x = bfpack(a.x, a.y);   d.y = bfpack(a.z, a.w);
            d.z = bfpack(bb.x, bb.y); d.w = bfpack(bb.z, bb.w);
            k_su[row * 8 + (c8 ^ (row & 7))] = d;
        }
    }
    const int r0g = q0 + 2 * w;              // this wave's two global q rows
    const float qv0 = Q[((size_t)(b * L_SEQ) + r0g)     * D_HEAD + ln];
    const float qv1 = Q[((size_t)(b * L_SEQ) + r0g + 1) * D_HEAD + ln];
    // zero the att row pad (cols 264..271) for vectorized phase E reads
    if (ln < 16) {
        int r = 2 * w + (ln >> 3);
        att[r * ATTS + 264 + (ln & 7)] = 0.f;
    }
    __syncthreads();                         // the ONLY block-wide barrier

    // ---------------- Phase B: scores; lane owns cols cg*64+ln --------------
    float p0[5], p1[5];
    {
        const uint4* kp[5];
        int msk[5];
        #pragma unroll
        for (int cg = 0; cg < 5; ++cg) {
            int colr = cg * 64 + ln;
            int col  = (colr < W) ? colr : W - 1;   // clamped for memory
            kp[cg]  = k_su + (size_t)col * 8;
            msk[cg] = col & 7;
            p0[cg] = 0.f; p1[cg] = 0.f;
        }
        #pragma unroll
        for (int c8 = 0; c8 < 8; ++c8) {
            // q[8c8 .. 8c8+7] for both rows, via v_readlane (VALU, no LDS pipe)
            float a0 = RL(qv0, 8*c8+0), a1 = RL(qv0, 8*c8+1),
                  a2 = RL(qv0, 8*c8+2), a3 = RL(qv0, 8*c8+3),
                  a4 = RL(qv0, 8*c8+4), a5 = RL(qv0, 8*c8+5),
                  a6 = RL(qv0, 8*c8+6), a7 = RL(qv0, 8*c8+7);
            float b0 = RL(qv1, 8*c8+0), b1 = RL(qv1, 8*c8+1),
                  b2 = RL(qv1, 8*c8+2), b3 = RL(qv1, 8*c8+3),
                  b4 = RL(qv1, 8*c8+4), b5 = RL(qv1, 8*c8+5),
                  b6 = RL(qv1, 8*c8+6), b7 = RL(qv1, 8*c8+7);
            #pragma unroll
            for (int cg = 0; cg < 5; ++cg) {
                uint4 kk = kp[cg][c8 ^ msk[cg]];
                float e0 = __uint_as_float(kk.x << 16);
                float e1 = __uint_as_float(kk.x & 0xffff0000u);
                float e2 = __uint_as_float(kk.y << 16);
                float e3 = __uint_as_float(kk.y & 0xffff0000u);
                float e4 = __uint_as_float(kk.z << 16);
                float e5 = __uint_as_float(kk.z & 0xffff0000u);
                float e6 = __uint_as_float(kk.w << 16);
                float e7 = __uint_as_float(kk.w & 0xffff0000u);
                p0[cg] += a0*e0 + a1*e1 + a2*e2 + a3*e3
                        + a4*e4 + a5*e5 + a6*e6 + a7*e7;
                p1[cg] += b0*e0 + b1*e1 + b2*e2 + b3*e3
                        + b4*e4 + b5*e5 + b6*e6 + b7*e7;
            }
        }
        #pragma unroll
        for (int cg = 0; cg < 5; ++cg) { p0[cg] *= SCALE; p1[cg] *= SCALE; }
    }

    // ---------------- Phase C: in-register masked softmax (per wave) --------
    {
        int st0 = r0g - M_WIN;
        if (st0 < 0) st0 = 0;
        if (st0 > L_SEQ - WIN) st0 = L_SEQ - WIN;
        const int lo0 = st0 - s0;
        int st1 = r0g + 1 - M_WIN;
        if (st1 < 0) st1 = 0;
        if (st1 > L_SEQ - WIN) st1 = L_SEQ - WIN;
        const int lo1 = st1 - s0;

        float m0 = -1e30f, m1 = -1e30f;
        #pragma unroll
        for (int cg = 0; cg < 5; ++cg) {
            int colr = cg * 64 + ln;
            bool in0 = (colr >= lo0) && (colr < lo0 + WIN);
            bool in1 = (colr >= lo1) && (colr < lo1 + WIN);
            p0[cg] = in0 ? p0[cg] : -1e30f;
            p1[cg] = in1 ? p1[cg] : -1e30f;
            m0 = fmaxf(m0, p0[cg]);
            m1 = fmaxf(m1, p1[cg]);
        }
        #pragma unroll
        for (int off = 32; off >= 1; off >>= 1) {
            m0 = fmaxf(m0, __shfl_xor(m0, off));
            m1 = fmaxf(m1, __shfl_xor(m1, off));
        }
        float sum0 = 0.f, sum1 = 0.f;
        #pragma unroll
        for (int cg = 0; cg < 5; ++cg) {
            float e0 = (p0[cg] <= -1e29f) ? 0.f : __expf(p0[cg] - m0);
            float e1 = (p1[cg] <= -1e29f) ? 0.f : __expf(p1[cg] - m1);
            p0[cg] = e0; p1[cg] = e1;
            sum0 += e0; sum1 += e1;
        }
        #pragma unroll
        for (int off = 32; off >= 1; off >>= 1) {
            sum0 += __shfl_xor(sum0, off);
            sum1 += __shfl_xor(sum1, off);
        }
        const float inv0 = 1.f / sum0, inv1 = 1.f / sum1;
        #pragma unroll
        for (int cg = 0; cg < 5; ++cg) {
            int colr = cg * 64 + ln;
            if (colr < W) {
                att[(2 * w)     * ATTS + colr] = p0[cg] * inv0;  // 0 outside win
                att[(2 * w + 1) * ATTS + colr] = p1[cg] * inv1;
            }
        }
    }
    // No barrier: everything below reads only this wave's own att rows.

    // ---------------- Phase E: PV; vectorized att reads (b128 per 4 cols) ---
    {
        const int cq = ln >> 4;              // which f4 of the 16-col group
        const int dg = ln & 15;              // d float4-group
        const float4* Vg4 = (const float4*)(V + ((size_t)(b * L_SEQ + s0)) * D_HEAD);
        const float4* a4r0 = (const float4*)(att + (2 * w) * ATTS);
        const float4* a4r1 = (const float4*)(att + (2 * w + 1) * ATTS);
        float4 acc0 = {0.f,0.f,0.f,0.f}, acc1 = {0.f,0.f,0.f,0.f};
        #pragma unroll 2
        for (int G = 0; G < 17; ++G) {       // 17*16 = 272 cols (pad p = 0)
            float4 pa = a4r0[4 * G + cq];
            float4 pb = a4r1[4 * G + cq];
            #pragma unroll
            for (int e = 0; e < 4; ++e) {
                int col  = 16 * G + 4 * cq + e;
                int colc = (col < wcount) ? col : wcount - 1;   // p is 0 there
                float4 vv = Vg4[(size_t)colc * 16 + dg];
                float fa = (e == 0) ? pa.x : (e == 1) ? pa.y : (e == 2) ? pa.z : pa.w;
                float fb = (e == 0) ? pb.x : (e == 1) ? pb.y : (e == 2) ? pb.z : pb.w;
                acc0.x += fa * vv.x; acc0.y += fa * vv.y;
                acc0.z += fa * vv.z; acc0.w += fa * vv.w;
                acc1.x += fb * vv.x; acc1.y += fb * vv.y;
                acc1.z += fb * vv.z; acc1.w += fb * vv.w;
            }
        }
        #pragma unroll
        for (int off = 16; off <= 32; off <<= 1) {
            acc0.x += __shfl_xor(acc0.x, off); acc0.y += __shfl_xor(acc0.y, off);
            acc0.z += __shfl_xor(acc0.z, off); acc0.w += __shfl_xor(acc0.w, off);
            acc1.x += __shfl_xor(acc1.x, off); acc1.y += __shfl_xor(acc1.y, off);
            acc1.z += __shfl_xor(acc1.z, off); acc1.w += __shfl_xor(acc1.w, off);
        }
        if (ln < 16) {
            float4* o4 = (float4*)(OutO + ((size_t)(b * L_SEQ + r0g)) * D_HEAD);
            o4[dg]      = acc0;
            o4[16 + dg] = acc1;
        }
    }

    // ---------------- Phase D: dense stream of this wave's 2 att rows -------
    if ((s0 & 3) == 0) {
        const int zlo = s0 >> 2;
        #pragma unroll
        for (int r = 0; r < 2; ++r) {
            float4* rowp = (float4*)(OutA + ((size_t)(b * L_SEQ + r0g + r)) * L_SEQ);
            const float4* arow = (const float4*)(att + (2 * w + r) * ATTS);
            #pragma unroll 4
            for (int j = 0; j < 16; ++j) {
                int f4i = j * 64 + ln;
                int u4  = f4i - zlo;
                float4 wv = {0.f,0.f,0.f,0.f};
                if (u4 >= 0 && u4 < WF4) wv = arow[u4];     // aligned b128 read
                rowp[f4i] = wv;                             // 1 KB/instr, clean
            }
        }
    } else {   // rare top-edge blocks (s0 = 3839)
        #pragma unroll
        for (int r = 0; r < 2; ++r) {
            float4* rowp = (float4*)(OutA + ((size_t)(b * L_SEQ + r0g + r)) * L_SEQ);
            const float* arow = att + (2 * w + r) * ATTS;
            #pragma unroll 2
            for (int j = 0; j < 16; ++j) {
                int f4i = j * 64 + ln;
                int u   = 4 * f4i - s0;
                float4 wv;
                wv.x = (u     >= 0 && u     < W) ? arow[u]     : 0.f;
                wv.y = (u + 1 >= 0 && u + 1 < W) ? arow[u + 1] : 0.f;
                wv.z = (u + 2 >= 0 && u + 2 < W) ? arow[u + 2] : 0.f;
                wv.w = (u + 3 >= 0 && u + 3 < W) ? arow[u + 3] : 0.f;
                rowp[f4i] = wv;
            }
        }
    }
}

extern "C" void kernel_launch(void* const* d_in, const int* in_sizes, int n_in,
                              void* d_out, int out_size, void* d_ws, size_t ws_size,
                              hipStream_t stream) {
    const float* Q = (const float*)d_in[0];
    const float* K = (const float*)d_in[1];
    const float* V = (const float*)d_in[2];
    float* OutO = (float*)d_out;
    float* OutA = OutO + (size_t)8 * L_SEQ * D_HEAD;

    const int smem_bytes = 2112 * 16 + QB * ATTS * 4;   // 42496 B
    hipFuncSetAttribute((const void*)win_attn_kernel,
                        hipFuncAttributeMaxDynamicSharedMemorySize, smem_bytes);

    dim3 grid(8 * (L_SEQ / QB));
    dim3 block(256);
    win_attn_kernel<<<grid, block, smem_bytes, stream>>>(Q, K, V, OutO, OutA);
}